// Round 6
// baseline (3665.287 us; speedup 1.0000x reference)
//
#include <hip/hip_runtime.h>
#include <hip/hip_bf16.h>
#include <math.h>

typedef __hip_bfloat16 bf16;
typedef __attribute__((ext_vector_type(8))) short short8;
typedef __attribute__((ext_vector_type(4))) float floatx4;

#define SEQ   128
#define BATCH 64
#define VOCAB 10000
#define HID   1024
#define TAIL  81920000   // SEQ*BATCH*VOCAB, element offset of h_final in d_out
#define PNL   131072     // one hidden panel: 64 rows * 1024 cols * 2B (bf16)
#define SPIN  (1 << 17)  // bounded spin: deadlock -> wrong answer, not hang

#define MFMA(a,b,c) __builtin_amdgcn_mfma_f32_16x16x32_bf16((a),(b),(c),0,0,0)

// Inter-block traffic: RELAXED agent-scope atomics (LLC-direct, no cache-
// maintenance ops). Proven correct in rounds 3/4. Ordering data->stamp via
// __syncthreads (vmcnt(0) drain) before the stamp store.
#define LDA_U64(p)   __hip_atomic_load((const unsigned long long*)(p), __ATOMIC_RELAXED, __HIP_MEMORY_SCOPE_AGENT)
#define LDA_I32(p)   __hip_atomic_load((const int*)(p), __ATOMIC_RELAXED, __HIP_MEMORY_SCOPE_AGENT)
#define STA_U32(p,v) __hip_atomic_store((unsigned int*)(p), (v), __ATOMIC_RELAXED, __HIP_MEMORY_SCOPE_AGENT)
#define STA_I32(p,v) __hip_atomic_store((int*)(p), (v), __ATOMIC_RELAXED, __HIP_MEMORY_SCOPE_AGENT)

union U16B { unsigned long long u[2]; short8 s; };

__device__ inline unsigned int pack2(float lo, float hi) {
  unsigned short a = __builtin_bit_cast(unsigned short, __float2bfloat16(lo));
  unsigned short b = __builtin_bit_cast(unsigned short, __float2bfloat16(hi));
  return ((unsigned int)b << 16) | (unsigned int)a;
}

__device__ inline void gl_lds16(const bf16* g, bf16* s) {
  __builtin_amdgcn_global_load_lds(
      (const __attribute__((address_space(1))) void*)g,
      (__attribute__((address_space(3))) void*)s, 16, 0, 0);
}

// read element i of an input tensor that is either fp32 (f=1) or bf16 (f=0)
__device__ inline float ld_in(const void* p, size_t i, int f) {
  return f ? ((const float*)p)[i] : __bfloat162float(((const bf16*)p)[i]);
}

// ---------------------------------------------------------------------------
// Detect input dtype. flag[0]=1 -> fp32, 0 -> bf16. Zeroes the stamp arrays:
//   s0 = flag+64   (64 blocks x 32-int lines)  h0-step stamps
//   s1 = flag+2112 (64 blocks x 32-int lines)  h1-step stamps
// ---------------------------------------------------------------------------
__global__ __launch_bounds__(256) void detect(const unsigned short* __restrict__ u,
                                              int* __restrict__ flag) {
  __shared__ int smax;
  if (threadIdx.x == 0) smax = 0;
  __syncthreads();
  int mymax = 0;
  for (int i = threadIdx.x * 2; i < 4096; i += 512) {   // even indices only
    int e = (u[i] >> 7) & 0xFF;
    mymax = max(mymax, e);
  }
  atomicMax(&smax, mymax);
  for (int i = threadIdx.x + 1; i < 4160; i += 256) flag[i] = 0;
  __syncthreads();
  if (threadIdx.x == 0) flag[0] = (smax >= 0xF0) ? 1 : 0;
}

// ---------------------------------------------------------------------------
__global__ __launch_bounds__(256) void convert_any(const void* __restrict__ src,
                                                   bf16* __restrict__ dst, int n,
                                                   const int* __restrict__ flagp) {
  int f = *flagp;
  for (int i = blockIdx.x * 256 + threadIdx.x; i < n; i += gridDim.x * 256)
    dst[i] = __float2bfloat16(ld_in(src, (size_t)i, f));
}

// initial hidden: h0[-1] -> H0 ring slot 3 (step 0 reads (0-1)&3 = 3),
//                 h1[-1] -> H1 ring slot 1 (step 1 reads (1-2)&1 = 1).
__global__ __launch_bounds__(256) void init_hidden(const void* __restrict__ src,
                                                   bf16* __restrict__ h0,
                                                   bf16* __restrict__ h1,
                                                   const int* __restrict__ flagp) {
  int f = *flagp;
  int i = blockIdx.x * 256 + threadIdx.x;
  if (i < 65536) {
    h0[i] = __float2bfloat16(ld_in(src, (size_t)i, f));
    h1[i] = __float2bfloat16(ld_in(src, (size_t)(65536 + i), f));
  }
}

// ---------------------------------------------------------------------------
// Transpose the 4 recurrence weight matrices into bf16 [n][k] (K-contiguous).
// Wt layout: z=0 Wx0^T, z=1 Wh0^T, z=2 Wx1^T, z=3 Wh1^T (each 1024x1024).
// ---------------------------------------------------------------------------
__global__ __launch_bounds__(256) void transpose4(const void* __restrict__ Wx,
                                                  const void* __restrict__ Wh,
                                                  bf16* __restrict__ Wt,
                                                  const int* __restrict__ flagp) {
  __shared__ bf16 tile[64][65];
  int f = *flagp;
  int z = blockIdx.z;
  const void* src = (z & 1) ? Wh : Wx;
  size_t loff = (z >> 1) ? (size_t)HID * HID : 0;
  bf16* dst = Wt + (size_t)z * HID * HID;
  int r0 = blockIdx.x * 64, c0 = blockIdx.y * 64;
  int t = threadIdx.x, cc = t & 63, rg = t >> 6;
  #pragma unroll
  for (int i = 0; i < 16; ++i) {
    int r = rg * 16 + i;
    tile[r][cc] = __float2bfloat16(ld_in(src, loff + (size_t)(r0 + r) * HID + c0 + cc, f));
  }
  __syncthreads();
  #pragma unroll
  for (int i = 0; i < 16; ++i) {
    int j = rg * 16 + i;
    dst[(size_t)(c0 + j) * HID + r0 + cc] = tile[cc][j];  // dst[j][k]=src[k][j]
  }
}

// ---------------------------------------------------------------------------
// A0 = emb[tok] @ Wx0 + b0   (fp32 out, [8192][1024]).  m97-style 128x128x32.
// ---------------------------------------------------------------------------
__global__ __launch_bounds__(256) void gemm_a0(
    const int*  __restrict__ tok,    // [8192]
    const bf16* __restrict__ emb,    // [VOCAB][HID] bf16
    const bf16* __restrict__ Wx0t,   // [HID][HID]  (n,k)
    const bf16* __restrict__ b0,     // [HID] bf16
    float* __restrict__ A0)          // [8192][HID]
{
  __shared__ __align__(16) bf16 sA[128 * 32];
  __shared__ __align__(16) bf16 sB[128 * 32];
  int m0 = blockIdx.x * 128, n0 = blockIdx.y * 128;
  int t = threadIdx.x, lane = t & 63, w = t >> 6;
  int wm = (w >> 1) * 64, wn = (w & 1) * 64;
  int quad = lane >> 4, l16 = lane & 15;

  int r0 = t >> 2, kc = t & 3;
  const bf16* ga0 = emb + (size_t)tok[m0 + r0] * HID + kc * 8;
  const bf16* ga1 = emb + (size_t)tok[m0 + r0 + 64] * HID + kc * 8;
  const bf16* gb0 = Wx0t + (size_t)(n0 + r0) * HID + kc * 8;
  const bf16* gb1 = gb0 + (size_t)64 * HID;
  bf16* sa0 = sA + t * 8;  bf16* sa1 = sA + (t + 256) * 8;
  bf16* sb0 = sB + t * 8;  bf16* sb1 = sB + (t + 256) * 8;

  floatx4 acc[4][4];
  #pragma unroll
  for (int j = 0; j < 4; ++j) {
    float bv = __bfloat162float(b0[n0 + wn + j * 16 + l16]);
    #pragma unroll
    for (int i = 0; i < 4; ++i) acc[i][j] = (floatx4){bv, bv, bv, bv};
  }

  for (int kt = 0; kt < 32; ++kt) {
    gl_lds16(ga0, sa0); gl_lds16(ga1, sa1);
    gl_lds16(gb0, sb0); gl_lds16(gb1, sb1);
    ga0 += 32; ga1 += 32; gb0 += 32; gb1 += 32;
    __syncthreads();
    short8 af[4], bfr[4];
    #pragma unroll
    for (int i = 0; i < 4; ++i)
      af[i] = *(const short8*)(sA + (wm + i * 16 + l16) * 32 + quad * 8);
    #pragma unroll
    for (int j = 0; j < 4; ++j)
      bfr[j] = *(const short8*)(sB + (wn + j * 16 + l16) * 32 + quad * 8);
    #pragma unroll
    for (int i = 0; i < 4; ++i)
      #pragma unroll
      for (int j = 0; j < 4; ++j)
        acc[i][j] = MFMA(af[i], bfr[j], acc[i][j]);
    __syncthreads();
  }

  #pragma unroll
  for (int i = 0; i < 4; ++i)
    #pragma unroll
    for (int j = 0; j < 4; ++j)
      #pragma unroll
      for (int r = 0; r < 4; ++r) {
        int row = wm + i * 16 + quad * 4 + r;
        int col = wn + j * 16 + l16;
        A0[(size_t)(m0 + row) * HID + n0 + col] = acc[i][j][r];
      }
}

// ---------------------------------------------------------------------------
// Persistent wavefront, SINGLE cohort of 64 blocks (16 cols each), both
// layers per block. Step r:
//   wait all s0 >= r                      (ONE critical spin per step)
//   h0[r]   = tanh(A0[r] + h0[r-1]@Wh0)   publish -> stamp s0 = r+1
//   wait all s1 >= r-1                    (usually pre-satisfied)
//   h1[r-1] = tanh(h0[r-1]@Wx1 + h1[r-2]@Wh1 + b1)  publish -> stamp s1 = r
// Program order h1(r-2) < s0-stamp(r) makes s0>=r imply s1>=r-2, which covers
// every ring WAR hazard (4-slot h0 ring, 2-slot h1 ring) -- derivation in
// round-6 notes. All blocks trivially co-resident (64 blocks, 96KB LDS).
// ---------------------------------------------------------------------------
__global__ __launch_bounds__(256) void wavefront_persist(
    const float* __restrict__ A0,
    const bf16* __restrict__ Wt,      // 4x[1024][1024]: Wx0t,Wh0t,Wx1t,Wh1t
    const bf16* __restrict__ bvecB,   // [2*HID] bf16
    char* __restrict__ H0r,           // 4-slot ring of bf16 panels [64][1024]
    char* __restrict__ H1r,           // 2-slot ring
    bf16* __restrict__ H1hist,        // [8192][HID] bf16 (for gemm_logits)
    void* __restrict__ outv,
    int* __restrict__ flagp)          // [0]=dtype, +64 s0[64], +2112 s1[64]
{
  __shared__ __align__(16) short8 sW8[6144];   // 96 KB: Wh0 | Wx1 | Wh1 slices
  char* sWb = (char*)sW8;
  const int f = flagp[0];
  int* s0 = flagp + 64;
  int* s1 = flagp + 2112;
  char* H1B = (char*)H1hist;
  const int blk = blockIdx.x;
  const int n0 = blk * 16;            // this block's 16 columns
  const int t = threadIdx.x, lane = t & 63, w = t >> 6;
  const int quad = lane >> 4, l16 = lane & 15;
  const int m = w * 16;               // wave w: rows m..m+15
  int* mys0 = s0 + blk * 32;
  int* mys1 = s1 + blk * 32;
  const int* ps0 = s0 + lane * 32;    // lane i polls block i's stamp
  const int* ps1 = s1 + lane * 32;

  const bf16* Wh0t = Wt + (size_t)1 * HID * HID;
  const bf16* Wx1t = Wt + (size_t)2 * HID * HID;
  const bf16* Wh1t = Wt + (size_t)3 * HID * HID;

  // ---- one-time LDS staging, MFMA-native: frag(kt) at kt*1024 + lane*16 ----
  #pragma unroll
  for (int i = 0; i < 8; ++i) {
    int idx = i * 256 + t;            // 0..2047: row 0..15, c16 0..127
    int row = idx >> 7, c16 = idx & 127;
    int off = (c16 >> 2) * 1024 + (c16 & 3) * 256 + (row & 15) * 16;
    *(short8*)(sWb + off)         = *(const short8*)(Wh0t + (size_t)(n0 + row) * HID + c16 * 8);
    *(short8*)(sWb + 32768 + off) = *(const short8*)(Wx1t + (size_t)(n0 + row) * HID + c16 * 8);
    *(short8*)(sWb + 65536 + off) = *(const short8*)(Wh1t + (size_t)(n0 + row) * HID + c16 * 8);
  }
  __syncthreads();

  const char* w0p = sWb + lane * 16;           // Wh0 frags, kt stride 1024
  const char* wXp = sWb + 32768 + lane * 16;   // Wx1
  const char* wHp = sWb + 65536 + lane * 16;   // Wh1
  const float bb = __bfloat162float(bvecB[HID + n0 + l16]);

  for (int r = 0; r <= 128; ++r) {
    // A0 addends issued before the spin (latency hides under it)
    float a0r[4];
    if (r <= 127) {
      #pragma unroll
      for (int q = 0; q < 4; ++q)
        a0r[q] = A0[(size_t)(r * 64 + m + quad * 4 + q) * HID + n0 + l16];
    }
    // ---- critical spin: everyone finished h0-part of step r-1 ----
    if (r >= 1) {
      if (w == 0) {
        int g = 0;
        while (!__all(LDA_I32(ps0) >= r) && ++g < SPIN)
          __builtin_amdgcn_s_sleep(2);
      }
      __syncthreads();
      __builtin_amdgcn_sched_barrier(0);
    }

    // =================== h0-part: h0[r] = tanh(A0 + h0[r-1]@Wh0) ==========
    if (r <= 127) {
      const char* xB = H0r + (size_t)((r - 1) & 3) * PNL + (m + l16) * 2048 + quad * 16;
      floatx4 accA = {}, accB = {};
      #pragma unroll
      for (int hf = 0; hf < 2; ++hf) {
        U16B x[16];
        #pragma unroll
        for (int i = 0; i < 16; ++i) {
          int kt = hf * 16 + i;
          x[i].u[0] = LDA_U64(xB + kt * 64);
          x[i].u[1] = LDA_U64(xB + kt * 64 + 8);
        }
        #pragma unroll
        for (int i = 0; i < 16; i += 2) {      // two interleaved dep chains
          int kt = hf * 16 + i;
          accA = MFMA(x[i].s,     *(const short8*)(w0p + kt * 1024),       accA);
          accB = MFMA(x[i + 1].s, *(const short8*)(w0p + (kt + 1) * 1024), accB);
        }
      }
      char* wp = H0r + (size_t)(r & 3) * PNL;
      #pragma unroll
      for (int q = 0; q < 4; ++q) {
        int row = m + quad * 4 + q, col = n0 + l16;
        float v = tanhf(accA[q] + accB[q] + a0r[q]);
        float pv = __shfl_xor(v, 1);
        if (r == 127) {                                          // h_final[0]
          size_t o = (size_t)TAIL + (size_t)row * HID + col;
          if (f) ((float*)outv)[o] = v;
          else   ((bf16*)outv)[o] = __float2bfloat16(v);
        }
        if (!(l16 & 1))
          STA_U32(wp + row * 2048 + col * 2, pack2(v, pv));
      }
      __syncthreads();                 // vmcnt(0): panel stores LLC-acked
      if (t == 0) STA_I32(mys0, r + 1);
    }

    // ====== h1-part: h1[r-1] = tanh(h0[r-1]@Wx1 + h1[r-2]@Wh1 + b1) =======
    if (r >= 1) {
      if (r >= 2) {                    // usually pre-satisfied (h1 lags h0)
        if (w == 0) {
          int g = 0;
          while (!__all(LDA_I32(ps1) >= r - 1) && ++g < SPIN)
            __builtin_amdgcn_s_sleep(2);
        }
        __syncthreads();
        __builtin_amdgcn_sched_barrier(0);
      }
      const char* xB = H0r + (size_t)((r - 1) & 3) * PNL + (m + l16) * 2048 + quad * 16;
      const char* hB = H1r + (size_t)((r - 2) & 1) * PNL + (m + l16) * 2048 + quad * 16;
      floatx4 accX = {}, accH = {};
      #pragma unroll
      for (int hf = 0; hf < 2; ++hf) {
        U16B x[16], h[16];
        #pragma unroll
        for (int i = 0; i < 16; ++i) {
          int kt = hf * 16 + i;
          x[i].u[0] = LDA_U64(xB + kt * 64);
          x[i].u[1] = LDA_U64(xB + kt * 64 + 8);
          h[i].u[0] = LDA_U64(hB + kt * 64);
          h[i].u[1] = LDA_U64(hB + kt * 64 + 8);
        }
        #pragma unroll
        for (int i = 0; i < 16; ++i) {
          int kt = hf * 16 + i;
          accX = MFMA(x[i].s, *(const short8*)(wXp + kt * 1024), accX);
          accH = MFMA(h[i].s, *(const short8*)(wHp + kt * 1024), accH);
        }
      }
      const int s = r - 1;
      char* wp = H1r + (size_t)(s & 1) * PNL;
      #pragma unroll
      for (int q = 0; q < 4; ++q) {
        int row = m + quad * 4 + q, col = n0 + l16;
        float v = tanhf(accX[q] + accH[q] + bb);
        float pv = __shfl_xor(v, 1);
        if (s == 127) {                                          // h_final[1]
          size_t o = (size_t)TAIL + 64 * HID + (size_t)row * HID + col;
          if (f) ((float*)outv)[o] = v;
          else   ((bf16*)outv)[o] = __float2bfloat16(v);
        }
        if (!(l16 & 1)) {
          unsigned int pk = pack2(v, pv);
          STA_U32(wp + row * 2048 + col * 2, pk);
          STA_U32(H1B + ((size_t)(s * 64 + row) * HID + col) * 2, pk);
        }
      }
      __syncthreads();
      if (t == 0) STA_I32(mys1, r);
    }
  }
}

// ---------------------------------------------------------------------------
// logits = H1 @ fcW^T + fcb  -> [8192][10000]. fcW already [V][K].
// ---------------------------------------------------------------------------
__global__ __launch_bounds__(256) void gemm_logits(
    const bf16* __restrict__ H1,    // [8192][HID]
    const bf16* __restrict__ fcW,   // [VOCAB][HID] bf16
    const bf16* __restrict__ fcb,   // [VOCAB] bf16
    void* __restrict__ outv,        // [8192][VOCAB] fp32 or bf16
    const int* __restrict__ flagp)
{
  __shared__ __align__(16) bf16 sA[128 * 32];
  __shared__ __align__(16) bf16 sB[128 * 32];
  int f = *flagp;
  int m0 = blockIdx.x * 128, n0 = blockIdx.y * 128;
  int t = threadIdx.x, lane = t & 63, w = t >> 6;
  int wm = (w >> 1) * 64, wn = (w & 1) * 64;
  int quad = lane >> 4, l16 = lane & 15;

  int r0 = t >> 2, kc = t & 3;
  int rB0 = n0 + r0;      if (rB0 > VOCAB - 1) rB0 = VOCAB - 1;
  int rB1 = n0 + r0 + 64; if (rB1 > VOCAB - 1) rB1 = VOCAB - 1;
  const bf16* ga0 = H1 + (size_t)(m0 + r0) * HID + kc * 8;
  const bf16* ga1 = ga0 + (size_t)64 * HID;
  const bf16* gb0 = fcW + (size_t)rB0 * HID + kc * 8;
  const bf16* gb1 = fcW + (size_t)rB1 * HID + kc * 8;
  bf16* sa0 = sA + t * 8;  bf16* sa1 = sA + (t + 256) * 8;
  bf16* sb0 = sB + t * 8;  bf16* sb1 = sB + (t + 256) * 8;

  floatx4 acc[4][4];
  #pragma unroll
  for (int j = 0; j < 4; ++j) {
    int c = n0 + wn + j * 16 + l16;
    float bv = __bfloat162float(fcb[c > VOCAB - 1 ? VOCAB - 1 : c]);
    #pragma unroll
    for (int i = 0; i < 4; ++i) acc[i][j] = (floatx4){bv, bv, bv, bv};
  }

  for (int kt = 0; kt < 32; ++kt) {
    gl_lds16(ga0, sa0); gl_lds16(ga1, sa1);
    gl_lds16(gb0, sb0); gl_lds16(gb1, sb1);
    ga0 += 32; ga1 += 32; gb0 += 32; gb1 += 32;
    __syncthreads();
    short8 af[4], bfr[4];
    #pragma unroll
    for (int i = 0; i < 4; ++i)
      af[i] = *(const short8*)(sA + (wm + i * 16 + l16) * 32 + quad * 8);
    #pragma unroll
    for (int j = 0; j < 4; ++j)
      bfr[j] = *(const short8*)(sB + (wn + j * 16 + l16) * 32 + quad * 8);
    #pragma unroll
    for (int i = 0; i < 4; ++i)
      #pragma unroll
      for (int j = 0; j < 4; ++j)
        acc[i][j] = MFMA(af[i], bfr[j], acc[i][j]);
    __syncthreads();
  }

  #pragma unroll
  for (int i = 0; i < 4; ++i)
    #pragma unroll
    for (int j = 0; j < 4; ++j)
      #pragma unroll
      for (int r = 0; r < 4; ++r) {
        int row = wm + i * 16 + quad * 4 + r;
        int col = n0 + wn + j * 16 + l16;
        if (col < VOCAB) {
          size_t o = (size_t)(m0 + row) * VOCAB + col;
          if (f) ((float*)outv)[o] = acc[i][j][r];
          else   ((bf16*)outv)[o] = __float2bfloat16(acc[i][j][r]);
        }
      }
}

// ---------------------------------------------------------------------------
extern "C" void kernel_launch(void* const* d_in, const int* in_sizes, int n_in,
                              void* d_out, int out_size, void* d_ws, size_t ws_size,
                              hipStream_t stream)
{
  const int*  tok     = (const int*)d_in[0];   // [128][64]
  const void* hid_raw = d_in[1];               // [2][64][1024]
  const void* emb_raw = d_in[2];               // [10000][1024]
  const void* Wx_raw  = d_in[3];               // [2][1024][1024]
  const void* Wh_raw  = d_in[4];               // [2][1024][1024]
  const void* b_raw   = d_in[5];               // [2][1024]
  const void* fcW_raw = d_in[6];               // [10000][1024]
  const void* fcb_raw = d_in[7];               // [10000]

  char* ws = (char*)d_ws;
  float* A0    = (float*)ws;                       //          0 : 33,554,432  fp32 8192x1024
  bf16*  Wt    = (bf16*)(ws + 33554432);           //  8,388,608 : 4x1024x1024 bf16
  bf16*  H1hist= (bf16*)(ws + 41943040);           // 16,777,216 : 8192x1024 bf16
  char*  H0r   = ws + 58720256;                    //    524,288 : 4-slot panel ring
  char*  H1r   = ws + 59244544;                    //    262,144 : 2-slot panel ring
  bf16*  shared= (bf16*)(ws + 59506688);           // 20,480,000 : embB, then fcwB
  bf16*  bvecB = (bf16*)(ws + 79986688);           //      4,096
  bf16*  fcbB  = (bf16*)(ws + 79990784);           //     20,000
  int*   flag  = (int*)(ws + 80010784);            //     16,640 : dtype + stamps

  detect<<<1, 256, 0, stream>>>((const unsigned short*)emb_raw, flag);
  convert_any<<<2048, 256, 0, stream>>>(emb_raw, shared, VOCAB * HID, flag);
  convert_any<<<8,    256, 0, stream>>>(b_raw,   bvecB, 2 * HID, flag);
  convert_any<<<40,   256, 0, stream>>>(fcb_raw, fcbB, VOCAB, flag);
  init_hidden<<<256, 256, 0, stream>>>(hid_raw, (bf16*)(H0r + 3 * PNL),
                                       (bf16*)(H1r + 1 * PNL), flag);
  transpose4<<<dim3(16, 16, 4), 256, 0, stream>>>(Wx_raw, Wh_raw, Wt, flag);
  gemm_a0<<<dim3(64, 8), 256, 0, stream>>>(tok, shared, Wt, bvecB, A0);
  // emb no longer needed -> reuse the buffer for fcW (stream-ordered)
  convert_any<<<2048, 256, 0, stream>>>(fcW_raw, shared, VOCAB * HID, flag);
  wavefront_persist<<<64, 256, 0, stream>>>(A0, Wt, bvecB, H0r, H1r,
                                            H1hist, d_out, flag);
  gemm_logits<<<dim3(64, 79), 256, 0, stream>>>(H1hist, shared, fcbB, d_out, flag);
}